// Round 8
// baseline (23427.316 us; speedup 1.0000x reference)
//
#include <hip/hip_runtime.h>

typedef _Float16 f16;
typedef _Float16 f16x4 __attribute__((ext_vector_type(4)));
typedef _Float16 f16x8 __attribute__((ext_vector_type(8)));
typedef float f32x4 __attribute__((ext_vector_type(4)));
typedef unsigned u32x4 __attribute__((ext_vector_type(4)));

#define SEQ 4096
#define NF  2048
#define HID 1024
#define SENT 0x7F800001u   // sNaN bit pattern: "not ready" sentinel (h is never NaN)

// ---------------- static device scratch ----------------
__device__ f16   g_Ahi[SEQ * NF];
__device__ f16   g_Alo[SEQ * NF];
__device__ f16   g_Whi[2 * 4096 * NF];
__device__ f16   g_Wlo[2 * 4096 * NF];
__device__ float g_xp [2u * SEQ * 4096u];          // [dir][t][4096]
__device__ float g_hist[2u * SEQ * HID];           // [dir][t][1024]
__device__ float g_ring[2][8][1024];               // [dir][slot][dim] : h bits or SENT
__device__ float g_feats[SEQ * 10];

// ---------------- fp32 -> f16 hi/lo split ----------------
__global__ void cvt_split(const float* __restrict__ src, int which, int n4) {
  int i = blockIdx.x * blockDim.x + threadIdx.x;
  int stride = gridDim.x * blockDim.x;
  f16* hi; f16* lo;
  if (which == 0)      { hi = g_Ahi; lo = g_Alo; }
  else if (which == 1) { hi = g_Whi; lo = g_Wlo; }
  else                 { hi = g_Whi + 4096 * NF; lo = g_Wlo + 4096 * NF; }
  const float4* s4 = (const float4*)src;
  f16x4* h4 = (f16x4*)hi;
  f16x4* l4 = (f16x4*)lo;
  for (int idx = i; idx < n4; idx += stride) {
    float4 v = s4[idx];
    f16x4 h, l;
    h.x = (f16)v.x; l.x = (f16)(v.x - (float)h.x);
    h.y = (f16)v.y; l.y = (f16)(v.y - (float)h.y);
    h.z = (f16)v.z; l.z = (f16)(v.z - (float)h.z);
    h.w = (f16)v.w; l.w = (f16)(v.w - (float)h.w);
    h4[idx] = h; l4[idx] = l;
  }
}

// ---------------- xp = A @ W^T + b  (split f16, 3 MFMA products) ----------------
__global__ __launch_bounds__(256, 1) void gemm_xp(
    const float* __restrict__ b_f, const float* __restrict__ b_b)
{
  const int d = blockIdx.z;
  const f16* WhiD = g_Whi + (size_t)d * (4096u * 2048u);
  const f16* WloD = g_Wlo + (size_t)d * (4096u * 2048u);
  const float* bias = d ? b_b : b_f;
  float* out = g_xp + (size_t)d * (4096u * 4096u);

  __shared__ f16 sAh[128 * 40];
  __shared__ f16 sAl[128 * 40];
  __shared__ f16 sWh[128 * 40];
  __shared__ f16 sWl[128 * 40];

  const int tid  = threadIdx.x;
  const int lane = tid & 63;
  const int wv   = tid >> 6;
  const int quad = lane >> 4;
  const int mrow = lane & 15;
  const int m0 = (wv & 1) * 64;
  const int n0 = (wv >> 1) * 64;
  const int bm = blockIdx.y, bn = blockIdx.x;

  f32x4 acc[4][4] = {};

  const int r0  = tid >> 2;
  const int seg = tid & 3;

  for (int kt = 0; kt < 2048; kt += 32) {
#pragma unroll
    for (int r = 0; r < 2; ++r) {
      int row = r * 64 + r0;
      size_t ga = (size_t)(bm * 128 + row) * 2048 + kt + seg * 8;
      size_t gw = (size_t)(bn * 128 + row) * 2048 + kt + seg * 8;
      int lidx = row * 40 + seg * 8;
      *(f16x8*)&sAh[lidx] = *(const f16x8*)&g_Ahi[ga];
      *(f16x8*)&sAl[lidx] = *(const f16x8*)&g_Alo[ga];
      *(f16x8*)&sWh[lidx] = *(const f16x8*)&WhiD[gw];
      *(f16x8*)&sWl[lidx] = *(const f16x8*)&WloD[gw];
    }
    __syncthreads();

    f16x8 ah[4], al[4], wh[4], wl[4];
#pragma unroll
    for (int mi = 0; mi < 4; ++mi) {
      int rowm = (m0 + mi * 16 + mrow) * 40 + quad * 8;
      ah[mi] = *(const f16x8*)&sAh[rowm];
      al[mi] = *(const f16x8*)&sAl[rowm];
    }
#pragma unroll
    for (int ni = 0; ni < 4; ++ni) {
      int rown = (n0 + ni * 16 + mrow) * 40 + quad * 8;
      wh[ni] = *(const f16x8*)&sWh[rown];
      wl[ni] = *(const f16x8*)&sWl[rown];
    }
#pragma unroll
    for (int mi = 0; mi < 4; ++mi)
#pragma unroll
      for (int ni = 0; ni < 4; ++ni) {
        acc[mi][ni] = __builtin_amdgcn_mfma_f32_16x16x32_f16(ah[mi], wh[ni], acc[mi][ni], 0, 0, 0);
        acc[mi][ni] = __builtin_amdgcn_mfma_f32_16x16x32_f16(ah[mi], wl[ni], acc[mi][ni], 0, 0, 0);
        acc[mi][ni] = __builtin_amdgcn_mfma_f32_16x16x32_f16(al[mi], wh[ni], acc[mi][ni], 0, 0, 0);
      }
    __syncthreads();
  }

#pragma unroll
  for (int ni = 0; ni < 4; ++ni) {
    int g = bn * 128 + n0 + ni * 16 + mrow;
    float bv = bias[g];
#pragma unroll
    for (int mi = 0; mi < 4; ++mi) {
#pragma unroll
      for (int r = 0; r < 4; ++r) {
        int t = bm * 128 + m0 + mi * 16 + quad * 4 + r;
        out[(size_t)t * 4096 + g] = acc[mi][ni][r] + bv;
      }
    }
  }
}

// ---------------- per-call ring reset (graph-replay safe) ----------------
// slot 0 = h_0 = 0.0f (real values, consumed at t=1); slots 1..7 = SENT.
__global__ void init_sync() {
  int i = blockIdx.x * blockDim.x + threadIdx.x;   // 0..16383
  int slot = (i >> 10) & 7;
  ((unsigned*)g_ring)[i] = (slot == 0) ? 0u : SENT;
}

// ---------------- persistent bidirectional LSTM ----------------
// R13 = R12's chain-shortened structure + the PROVEN poll implementation.
// R12's absmax=inf root cause [guide §5 rule #18]: the 2-deep poll used
// `s_waitcnt vmcnt(1)` as a SEPARATE asm statement; hipcc may schedule the
// register-only SENT-compares / LDS-store data reads across an inline-asm
// waitcnt (memory clobber doesn't order register reads) -> not-yet-landed
// register contents consumed as h -> NaN. Every passing round (R5/R7/R11)
// fused load+waitcnt into ONE asm block, making the ISA order load->wait->
// consume unconditionally correct. R13 reverts to exactly that poll.
// Retained from R12 (structurally validated in passing rounds):
//  1. per-wave dim ownership: wave w == local dim, lane-group == gate;
//     in-wave shfl_xor reduce + 4 shfl gathers -> no gates_lds, no 2nd
//     barrier, no 16-thread serial update; each wave's ring store departs
//     as soon as ITS GEMV finishes (straggler decoupling).
//  2. h_lds[2] double buffer -> ONE barrier/step. Same-buffer reuse (t+2)
//     fenced by the production chain: loaders pass poll t+1 only if all
//     WGs stored h_{t+1}, which requires their waves past barrier t+1,
//     which requires all GEMV_t reads of this buffer done.
//  3. grid 256 x 1024, dir = bid&3 (R11's placement: 2 XCD-epochs/dir).
// Protocol bytes unchanged: sNaN sentinel, 8 slots, re-arm t+4, agent-scope
// sc0 sc1 -> correctness placement-independent (R7/R11 proven).
__global__ __launch_bounds__(1024) void lstm_persistent(
    const float* __restrict__ Whh_f, const float* __restrict__ Whh_b)
{
  const int bid = blockIdx.x;
  const int dir = bid & 3;
  if (dir >= 2) return;            // 128 of 256 WGs exit immediately
  const int wsl = bid >> 2;        // 0..63 (dims [16*wsl, 16*wsl+16))
  const int tid  = threadIdx.x;
  const int w    = tid >> 6;       // wave index == local dim 0..15
  const int lane = tid & 63;
  const int g    = lane >> 4;      // gate 0..3 (16-lane group)
  const int l16  = lane & 15;

  __shared__ float h_lds[2][1024];

  const float* Wd = dir ? Whh_b : Whh_f;
  const int dim  = wsl * 16 + w;       // global h dim 0..1023
  const int grow = g * 1024 + dim;     // W_hh row for this lane-group

  // one-time weight load: row grow, cols 4*l16 + 64*j
  float4 w4[16];
#pragma unroll
  for (int j = 0; j < 16; ++j)
    w4[j] = *(const float4*)&Wd[(size_t)grow * 1024 + 4 * l16 + 64 * j];

  const float* xpd = g_xp + (size_t)dir * 4096u * 4096u;
  float* histd = g_hist + (size_t)dir * 4096u * 1024u;
  float* ringd = &g_ring[dir][0][0];   // [slot][1024]

  float c = 0.f;

  for (int t = 1; t <= 4096; ++t) {
    const int tau = dir ? (4096 - t) : (t - 1);
    const int b   = (t - 1) & 1;       // h_{t-1} buffer

    // poll ring for h_{t-1}: waves 0-3 (256 loaders), 4 dims (16B) each.
    // PROVEN fused pattern: load + s_waitcnt vmcnt(0) in ONE asm block
    // (ISA order load->wait guaranteed; register consume only after).
    if (w < 4) {
      const float* rs = ringd + (size_t)((t - 1) & 7) * 1024 + 4 * tid;
      u32x4 q;
      for (;;) {
        asm volatile("global_load_dwordx4 %0, %1, off sc0 sc1\n\t"
                     "s_waitcnt vmcnt(0)"
                     : "=v"(q) : "v"(rs) : "memory");
        if (q.x != SENT && q.y != SENT && q.z != SENT && q.w != SENT) break;
        __builtin_amdgcn_s_sleep(1);
      }
      float4 hv;
      hv.x = __uint_as_float(q.x);
      hv.y = __uint_as_float(q.y);
      hv.z = __uint_as_float(q.z);
      hv.w = __uint_as_float(q.w);
      *(float4*)&h_lds[b][4 * tid] = hv;
    }
    // xp for this lane's gate/dim (4 unique addrs/wave, HW-broadcast);
    // consumed after GEMV -> latency hides under barrier wait + GEMV.
    float xv = xpd[(size_t)tau * 4096 + g * 1024 + dim];
    __syncthreads();   // the ONLY barrier per step

    // GEMV: row grow, 64 k per thread (4-way ILP), h broadcast from LDS
    float p0 = 0.f, p1 = 0.f, p2 = 0.f, p3 = 0.f;
#pragma unroll
    for (int j = 0; j < 16; j += 4) {
      float4 h0 = *(const float4*)&h_lds[b][4 * l16 + 64 * (j + 0)];
      float4 h1 = *(const float4*)&h_lds[b][4 * l16 + 64 * (j + 1)];
      float4 h2 = *(const float4*)&h_lds[b][4 * l16 + 64 * (j + 2)];
      float4 h3 = *(const float4*)&h_lds[b][4 * l16 + 64 * (j + 3)];
      p0 += w4[j+0].x*h0.x + w4[j+0].y*h0.y + w4[j+0].z*h0.z + w4[j+0].w*h0.w;
      p1 += w4[j+1].x*h1.x + w4[j+1].y*h1.y + w4[j+1].z*h1.z + w4[j+1].w*h1.w;
      p2 += w4[j+2].x*h2.x + w4[j+2].y*h2.y + w4[j+2].z*h2.z + w4[j+2].w*h2.w;
      p3 += w4[j+3].x*h3.x + w4[j+3].y*h3.y + w4[j+3].z*h3.z + w4[j+3].w*h3.w;
    }
    float val = (p0 + p1) + (p2 + p3);
    // 16-lane row reduce: all 16 lanes of the gate group end with the sum
    val += __shfl_xor(val, 1);
    val += __shfl_xor(val, 2);
    val += __shfl_xor(val, 4);
    val += __shfl_xor(val, 8);
    val += xv;                        // add xp (uniform within group)
    // gather the 4 gate totals of dim w (all within this wave)
    float gi = __shfl(val, l16);
    float gf = __shfl(val, l16 + 16);
    float gg = __shfl(val, l16 + 32);
    float go = __shfl(val, l16 + 48);
    // cell update, redundantly in all 64 lanes (identical values)
    float si = 1.f / (1.f + __expf(-gi));
    float sf = 1.f / (1.f + __expf(-gf));
    float so = 1.f / (1.f + __expf(-go));
    float tg = 1.f - 2.f / (1.f + __expf(2.f * gg));
    c = sf * c + si * tg;
    float th = 1.f - 2.f / (1.f + __expf(2.f * c));
    float h  = so * th;
    if (lane == 0) {
      // ring store FIRST (the critical chain), raw 4B f32 bits
      __hip_atomic_store((unsigned*)&ringd[(size_t)(t & 7) * 1024 + dim],
                         __float_as_uint(h),
                         __ATOMIC_RELAXED, __HIP_MEMORY_SCOPE_AGENT);
      // re-arm the slot 4 steps ahead (off critical path; same-thread
      // same-address ordering + the production chain make it safe)
      if (t + 4 <= 4096)
        __hip_atomic_store((unsigned*)&ringd[(size_t)((t + 4) & 7) * 1024 + dim],
                           SENT,
                           __ATOMIC_RELAXED, __HIP_MEMORY_SCOPE_AGENT);
      histd[(size_t)tau * 1024 + dim] = h;
    }
    // no trailing barrier: next step's h_lds writes hit the other buffer;
    // same-buffer reuse (t+2) is fenced by the production chain (see top).
  }
}

// ---------------- feats = concat(h_f,h_b) @ W_lin^T + b_lin ----------------
__global__ __launch_bounds__(256, 1) void feats_kernel(
    const float* __restrict__ W_lin, const float* __restrict__ b_lin)
{
  const int tid = threadIdx.x;
  const int wv = tid >> 6, l = tid & 63;
  const int t0 = blockIdx.x * 16 + wv * 4;
  for (int it = 0; it < 4; ++it) {
    const int t = t0 + it;
    float hf[16], hbv[16];
#pragma unroll
    for (int i = 0; i < 16; ++i) hf[i]  = g_hist[(size_t)t * 1024 + l + 64 * i];
#pragma unroll
    for (int i = 0; i < 16; ++i) hbv[i] = g_hist[(size_t)(4096 + t) * 1024 + l + 64 * i];
#pragma unroll
    for (int tag = 0; tag < 10; ++tag) {
      float a = 0.f;
#pragma unroll
      for (int i = 0; i < 16; ++i) {
        a += W_lin[tag * 2048 + l + 64 * i] * hf[i];
        a += W_lin[tag * 2048 + 1024 + l + 64 * i] * hbv[i];
      }
      a += __shfl_xor(a, 32); a += __shfl_xor(a, 16); a += __shfl_xor(a, 8);
      a += __shfl_xor(a, 4);  a += __shfl_xor(a, 2);  a += __shfl_xor(a, 1);
      if (l == 0) g_feats[t * 10 + tag] = a + b_lin[tag];
    }
  }
}

// ---------------- Viterbi forward + backtrack ----------------
__global__ __launch_bounds__(64, 1) void viterbi_kernel(
    const float* __restrict__ trans, float* __restrict__ out)
{
  __shared__ unsigned char bps[4096 * 10];
  const int to = threadIdx.x;
  float tr[10];
#pragma unroll
  for (int f = 0; f < 10; ++f) tr[f] = (to < 10) ? trans[to * 10 + f] : 0.f;
  float fv = (to == 8) ? 0.f : -10000.f;   // START_TAG = 8

  float fbuf[8];
#pragma unroll
  for (int i = 0; i < 8; ++i) fbuf[i] = (to < 10) ? g_feats[i * 10 + to] : 0.f;

  for (int t = 0; t < 4096; t += 8) {
#pragma unroll
    for (int u = 0; u < 8; ++u) {
      const int tt = t + u;
      float m = -3.4e38f; int am = 0;
#pragma unroll
      for (int f = 0; f < 10; ++f) {
        float v = __shfl(fv, f) + tr[f];
        if (v > m) { m = v; am = f; }
      }
      float ft = fbuf[u];
      if (tt + 8 < 4096 && to < 10) fbuf[u] = g_feats[(tt + 8) * 10 + to];
      fv = m + ft;
      if (to < 10) bps[tt * 10 + to] = (unsigned char)am;
    }
  }
  __syncthreads();

  float term = fv + ((to < 10) ? trans[90 + to] : -3.4e38f);  // STOP_TAG row
  float best = -3.4e38f; int bl = 0;
#pragma unroll
  for (int f = 0; f < 10; ++f) {
    float v = __shfl(term, f);
    if (v > best) { best = v; bl = f; }
  }
  if (to == 0) {
    out[0] = best;
    int tag = bl;
    for (int t = 4095; t >= 0; --t) {
      out[1 + t] = (float)tag;
      tag = bps[t * 10 + tag];
    }
  }
}

// ---------------- launch ----------------
extern "C" void kernel_launch(void* const* d_in, const int* in_sizes, int n_in,
                              void* d_out, int out_size, void* d_ws, size_t ws_size,
                              hipStream_t stream)
{
  (void)in_sizes; (void)n_in; (void)out_size; (void)d_ws; (void)ws_size;
  const float* W_hh_f   = (const float*)d_in[2];
  const float* b_f      = (const float*)d_in[3];
  const float* W_hh_b   = (const float*)d_in[5];
  const float* b_b      = (const float*)d_in[6];
  const float* W_lin    = (const float*)d_in[7];
  const float* b_lin    = (const float*)d_in[8];
  const float* trans    = (const float*)d_in[9];

  cvt_split<<<1024, 256, 0, stream>>>((const float*)d_in[0], 0, 2097152);
  cvt_split<<<1024, 256, 0, stream>>>((const float*)d_in[1], 1, 2097152);
  cvt_split<<<1024, 256, 0, stream>>>((const float*)d_in[4], 2, 2097152);

  gemm_xp<<<dim3(32, 32, 2), 256, 0, stream>>>(b_f, b_b);

  init_sync<<<16, 1024, 0, stream>>>();

  lstm_persistent<<<256, 1024, 0, stream>>>(W_hh_f, W_hh_b);

  feats_kernel<<<256, 256, 0, stream>>>(W_lin, b_lin);

  viterbi_kernel<<<1, 64, 0, stream>>>(trans, (float*)d_out);
}

// Round 9
// 12243.945 us; speedup vs baseline: 1.9134x; 1.9134x over previous
//
#include <hip/hip_runtime.h>

typedef _Float16 f16;
typedef _Float16 f16x4 __attribute__((ext_vector_type(4)));
typedef _Float16 f16x8 __attribute__((ext_vector_type(8)));
typedef float f32x4 __attribute__((ext_vector_type(4)));
typedef unsigned u32x4 __attribute__((ext_vector_type(4)));

#define SEQ 4096
#define NF  2048
#define HID 1024
#define SENT 0x7F800001u   // sNaN bit pattern: "not ready" sentinel (h is never NaN)

// ---------------- static device scratch ----------------
__device__ f16   g_Ahi[SEQ * NF];
__device__ f16   g_Alo[SEQ * NF];
__device__ f16   g_Whi[2 * 4096 * NF];
__device__ f16   g_Wlo[2 * 4096 * NF];
__device__ float g_xp [2u * SEQ * 4096u];          // [dir][t][4096]
__device__ float g_hist[2u * SEQ * HID];           // [dir][t][1024]
__device__ float g_ring[2][8][1024];               // [dir][slot][dim] : h bits or SENT
__device__ float g_feats[SEQ * 10];

// ---------------- fp32 -> f16 hi/lo split ----------------
__global__ void cvt_split(const float* __restrict__ src, int which, int n4) {
  int i = blockIdx.x * blockDim.x + threadIdx.x;
  int stride = gridDim.x * blockDim.x;
  f16* hi; f16* lo;
  if (which == 0)      { hi = g_Ahi; lo = g_Alo; }
  else if (which == 1) { hi = g_Whi; lo = g_Wlo; }
  else                 { hi = g_Whi + 4096 * NF; lo = g_Wlo + 4096 * NF; }
  const float4* s4 = (const float4*)src;
  f16x4* h4 = (f16x4*)hi;
  f16x4* l4 = (f16x4*)lo;
  for (int idx = i; idx < n4; idx += stride) {
    float4 v = s4[idx];
    f16x4 h, l;
    h.x = (f16)v.x; l.x = (f16)(v.x - (float)h.x);
    h.y = (f16)v.y; l.y = (f16)(v.y - (float)h.y);
    h.z = (f16)v.z; l.z = (f16)(v.z - (float)h.z);
    h.w = (f16)v.w; l.w = (f16)(v.w - (float)h.w);
    h4[idx] = h; l4[idx] = l;
  }
}

// ---------------- xp = A @ W^T + b  (split f16, 3 MFMA products) ----------------
__global__ __launch_bounds__(256, 1) void gemm_xp(
    const float* __restrict__ b_f, const float* __restrict__ b_b)
{
  const int d = blockIdx.z;
  const f16* WhiD = g_Whi + (size_t)d * (4096u * 2048u);
  const f16* WloD = g_Wlo + (size_t)d * (4096u * 2048u);
  const float* bias = d ? b_b : b_f;
  float* out = g_xp + (size_t)d * (4096u * 4096u);

  __shared__ f16 sAh[128 * 40];
  __shared__ f16 sAl[128 * 40];
  __shared__ f16 sWh[128 * 40];
  __shared__ f16 sWl[128 * 40];

  const int tid  = threadIdx.x;
  const int lane = tid & 63;
  const int wv   = tid >> 6;
  const int quad = lane >> 4;
  const int mrow = lane & 15;
  const int m0 = (wv & 1) * 64;
  const int n0 = (wv >> 1) * 64;
  const int bm = blockIdx.y, bn = blockIdx.x;

  f32x4 acc[4][4] = {};

  const int r0  = tid >> 2;
  const int seg = tid & 3;

  for (int kt = 0; kt < 2048; kt += 32) {
#pragma unroll
    for (int r = 0; r < 2; ++r) {
      int row = r * 64 + r0;
      size_t ga = (size_t)(bm * 128 + row) * 2048 + kt + seg * 8;
      size_t gw = (size_t)(bn * 128 + row) * 2048 + kt + seg * 8;
      int lidx = row * 40 + seg * 8;
      *(f16x8*)&sAh[lidx] = *(const f16x8*)&g_Ahi[ga];
      *(f16x8*)&sAl[lidx] = *(const f16x8*)&g_Alo[ga];
      *(f16x8*)&sWh[lidx] = *(const f16x8*)&WhiD[gw];
      *(f16x8*)&sWl[lidx] = *(const f16x8*)&WloD[gw];
    }
    __syncthreads();

    f16x8 ah[4], al[4], wh[4], wl[4];
#pragma unroll
    for (int mi = 0; mi < 4; ++mi) {
      int rowm = (m0 + mi * 16 + mrow) * 40 + quad * 8;
      ah[mi] = *(const f16x8*)&sAh[rowm];
      al[mi] = *(const f16x8*)&sAl[rowm];
    }
#pragma unroll
    for (int ni = 0; ni < 4; ++ni) {
      int rown = (n0 + ni * 16 + mrow) * 40 + quad * 8;
      wh[ni] = *(const f16x8*)&sWh[rown];
      wl[ni] = *(const f16x8*)&sWl[rown];
    }
#pragma unroll
    for (int mi = 0; mi < 4; ++mi)
#pragma unroll
      for (int ni = 0; ni < 4; ++ni) {
        acc[mi][ni] = __builtin_amdgcn_mfma_f32_16x16x32_f16(ah[mi], wh[ni], acc[mi][ni], 0, 0, 0);
        acc[mi][ni] = __builtin_amdgcn_mfma_f32_16x16x32_f16(ah[mi], wl[ni], acc[mi][ni], 0, 0, 0);
        acc[mi][ni] = __builtin_amdgcn_mfma_f32_16x16x32_f16(al[mi], wh[ni], acc[mi][ni], 0, 0, 0);
      }
    __syncthreads();
  }

#pragma unroll
  for (int ni = 0; ni < 4; ++ni) {
    int g = bn * 128 + n0 + ni * 16 + mrow;
    float bv = bias[g];
#pragma unroll
    for (int mi = 0; mi < 4; ++mi) {
#pragma unroll
      for (int r = 0; r < 4; ++r) {
        int t = bm * 128 + m0 + mi * 16 + quad * 4 + r;
        out[(size_t)t * 4096 + g] = acc[mi][ni][r] + bv;
      }
    }
  }
}

// ---------------- per-call ring reset (graph-replay safe) ----------------
// slot 0 = h_0 = 0.0f (real values, consumed at t=1); slots 1..7 = SENT.
__global__ void init_sync() {
  int i = blockIdx.x * blockDim.x + threadIdx.x;   // 0..16383
  int slot = (i >> 10) & 7;
  ((unsigned*)g_ring)[i] = (slot == 0) ? 0u : SENT;
}

// ---------------- persistent bidirectional LSTM ----------------
// R14 = R11 (proven 8.78 ms: 2 barriers, serial tid<16 update, single-wave
// COALESCED 64B stores — R13 proved uncoalesced per-wave stores cost 2.5x
// via 16 serialized line epochs at the coherence point) with ONE change:
// the poll is 2-deep pipelined. R11's budget: GEMV ~0.35us, barriers+
// update+store ~0.3us of the 2.15us step -> detect dominates (~RTT +
// period/2 with the 1-deep poll). 2-deep: two in-flight 16B loads,
// counted s_waitcnt vmcnt(1) checks the older -> sampling period ~RTT/2.
// Compiler-safety per guide rule #18 (R12's absmax=inf root cause):
// __builtin_amdgcn_sched_barrier(0) immediately after EVERY counted
// waitcnt (stops register reads hoisting past the inline-asm wait);
// wave-uniform __all exit keeps the vmcnt-count invariant; vmcnt(0) drain
// + keep-alive on exit. xp prefetch moved after the poll (keeps the
// counted queue clean; placement validated in R13; latency hides under
// barrier1+GEMV+barrier2).
__global__ __launch_bounds__(1024) void lstm_persistent(
    const float* __restrict__ Whh_f, const float* __restrict__ Whh_b)
{
  const int bid = blockIdx.x;
  const int dir = bid & 3;
  if (dir >= 2) return;            // 128 of 256 WGs exit immediately
  const int wsl = bid >> 2;        // 0..63 (dims [16*wsl, 16*wsl+16))
  const int tid = threadIdx.x;
  const int r   = tid >> 4;        // local row 0..63 (gate = r>>4, jj = r&15)
  const int l16 = tid & 15;

  __shared__ float h_lds[1024];
  __shared__ float gates_lds[64];

  const float* Wd = dir ? Whh_b : Whh_f;

  // one-time weight load: row grow, cols 4*l16 + 64*j
  const int grow = (r >> 4) * 1024 + wsl * 16 + (r & 15);
  float4 w4[16];
#pragma unroll
  for (int j = 0; j < 16; ++j)
    w4[j] = *(const float4*)&Wd[(size_t)grow * 1024 + 4 * l16 + 64 * j];

  const float* xpd = g_xp + (size_t)dir * 4096u * 4096u;
  float* histd = g_hist + (size_t)dir * 4096u * 1024u;
  float* ringd = &g_ring[dir][0][0];   // [slot][1024]

  float c = 0.f;

  for (int t = 1; t <= 4096; ++t) {
    const int tau = dir ? (4096 - t) : (t - 1);

    // poll ring for h_{t-1}: 256 loader threads, 4 dims (16B) each.
    // 2-deep pipelined with rule-#18-safe fencing (sched_barrier(0) after
    // each counted waitcnt). Wave-uniform __all exit.
    float xv0 = 0.f, xv1 = 0.f, xv2 = 0.f, xv3 = 0.f;
    if (tid < 256) {
      const float* rs = ringd + (size_t)((t - 1) & 7) * 1024 + 4 * tid;
      u32x4 qa, qb, q;
      asm volatile("global_load_dwordx4 %0, %1, off sc0 sc1" : "=v"(qa) : "v"(rs) : "memory");
      asm volatile("global_load_dwordx4 %0, %1, off sc0 sc1" : "=v"(qb) : "v"(rs) : "memory");
      for (;;) {
        asm volatile("s_waitcnt vmcnt(1)" ::: "memory");
        __builtin_amdgcn_sched_barrier(0);
        if (__all(qa.x != SENT && qa.y != SENT && qa.z != SENT && qa.w != SENT)) { q = qa; break; }
        asm volatile("global_load_dwordx4 %0, %1, off sc0 sc1" : "=v"(qa) : "v"(rs) : "memory");
        asm volatile("s_waitcnt vmcnt(1)" ::: "memory");
        __builtin_amdgcn_sched_barrier(0);
        if (__all(qb.x != SENT && qb.y != SENT && qb.z != SENT && qb.w != SENT)) { q = qb; break; }
        asm volatile("global_load_dwordx4 %0, %1, off sc0 sc1" : "=v"(qb) : "v"(rs) : "memory");
        __builtin_amdgcn_s_sleep(1);
      }
      asm volatile("s_waitcnt vmcnt(0)" ::: "memory");   // drain dead slot
      __builtin_amdgcn_sched_barrier(0);
      asm volatile("" :: "v"(qa), "v"(qb));              // keep regs live
      float4 hv;
      hv.x = __uint_as_float(q.x);
      hv.y = __uint_as_float(q.y);
      hv.z = __uint_as_float(q.z);
      hv.w = __uint_as_float(q.w);
      *(float4*)&h_lds[4 * tid] = hv;
      // xp prefetch AFTER the poll (keeps the counted vmem queue clean);
      // consumed in the update stage -> hides under barrier1+GEMV+barrier2.
      if (tid < 16) {
        const float* px = xpd + (size_t)tau * 4096 + wsl * 16 + tid;
        xv0 = px[0]; xv1 = px[1024]; xv2 = px[2048]; xv3 = px[3072];
      }
    }
    __syncthreads();

    // GEMV: 1 row x 64 k per thread, 4-way ILP partials
    float p0 = 0.f, p1 = 0.f, p2 = 0.f, p3 = 0.f;
#pragma unroll
    for (int j = 0; j < 16; j += 4) {
      float4 h0 = *(const float4*)&h_lds[4 * l16 + 64 * (j + 0)];
      float4 h1 = *(const float4*)&h_lds[4 * l16 + 64 * (j + 1)];
      float4 h2 = *(const float4*)&h_lds[4 * l16 + 64 * (j + 2)];
      float4 h3 = *(const float4*)&h_lds[4 * l16 + 64 * (j + 3)];
      p0 += w4[j+0].x*h0.x + w4[j+0].y*h0.y + w4[j+0].z*h0.z + w4[j+0].w*h0.w;
      p1 += w4[j+1].x*h1.x + w4[j+1].y*h1.y + w4[j+1].z*h1.z + w4[j+1].w*h1.w;
      p2 += w4[j+2].x*h2.x + w4[j+2].y*h2.y + w4[j+2].z*h2.z + w4[j+2].w*h2.w;
      p3 += w4[j+3].x*h3.x + w4[j+3].y*h3.y + w4[j+3].z*h3.z + w4[j+3].w*h3.w;
    }
    float acc = (p0 + p1) + (p2 + p3);
    acc += __shfl_xor(acc, 1);
    acc += __shfl_xor(acc, 2);
    acc += __shfl_xor(acc, 4);
    acc += __shfl_xor(acc, 8);
    if (l16 == 0) gates_lds[r] = acc;
    __syncthreads();

    // cell update: 16 h-dims, one per thread 0..15 (single-wave, so the
    // ring/hist stores below stay COALESCED 64B single transactions)
    if (tid < 16) {
      float gi = gates_lds[tid]      + xv0;
      float gf = gates_lds[16 + tid] + xv1;
      float gg = gates_lds[32 + tid] + xv2;
      float go = gates_lds[48 + tid] + xv3;
      float si = 1.f / (1.f + __expf(-gi));
      float sf = 1.f / (1.f + __expf(-gf));
      float so = 1.f / (1.f + __expf(-go));
      float tg = 1.f - 2.f / (1.f + __expf(2.f * gg));
      c = sf * c + si * tg;
      float th = 1.f - 2.f / (1.f + __expf(2.f * c));
      float h  = so * th;
      const int dim = wsl * 16 + tid;
      // ring store FIRST (the critical chain), raw 4B f32 bits
      __hip_atomic_store((unsigned*)&ringd[(size_t)(t & 7) * 1024 + dim],
                         __float_as_uint(h),
                         __ATOMIC_RELAXED, __HIP_MEMORY_SCOPE_AGENT);
      // re-arm the slot 4 steps ahead (off critical path; same-thread
      // same-address ordering + the production chain make it safe)
      if (t + 4 <= 4096)
        __hip_atomic_store((unsigned*)&ringd[(size_t)((t + 4) & 7) * 1024 + dim],
                           SENT,
                           __ATOMIC_RELAXED, __HIP_MEMORY_SCOPE_AGENT);
      histd[(size_t)tau * 1024 + dim] = h;
    }
    // no trailing barrier: h_lds rewrites in t+1 are fenced by the post-GEMV
    // barrier of step t; gates_lds rewrites by the post-poll barrier of t+1.
  }
}

// ---------------- feats = concat(h_f,h_b) @ W_lin^T + b_lin ----------------
__global__ __launch_bounds__(256, 1) void feats_kernel(
    const float* __restrict__ W_lin, const float* __restrict__ b_lin)
{
  const int tid = threadIdx.x;
  const int wv = tid >> 6, l = tid & 63;
  const int t0 = blockIdx.x * 16 + wv * 4;
  for (int it = 0; it < 4; ++it) {
    const int t = t0 + it;
    float hf[16], hbv[16];
#pragma unroll
    for (int i = 0; i < 16; ++i) hf[i]  = g_hist[(size_t)t * 1024 + l + 64 * i];
#pragma unroll
    for (int i = 0; i < 16; ++i) hbv[i] = g_hist[(size_t)(4096 + t) * 1024 + l + 64 * i];
#pragma unroll
    for (int tag = 0; tag < 10; ++tag) {
      float a = 0.f;
#pragma unroll
      for (int i = 0; i < 16; ++i) {
        a += W_lin[tag * 2048 + l + 64 * i] * hf[i];
        a += W_lin[tag * 2048 + 1024 + l + 64 * i] * hbv[i];
      }
      a += __shfl_xor(a, 32); a += __shfl_xor(a, 16); a += __shfl_xor(a, 8);
      a += __shfl_xor(a, 4);  a += __shfl_xor(a, 2);  a += __shfl_xor(a, 1);
      if (l == 0) g_feats[t * 10 + tag] = a + b_lin[tag];
    }
  }
}

// ---------------- Viterbi forward + backtrack ----------------
__global__ __launch_bounds__(64, 1) void viterbi_kernel(
    const float* __restrict__ trans, float* __restrict__ out)
{
  __shared__ unsigned char bps[4096 * 10];
  const int to = threadIdx.x;
  float tr[10];
#pragma unroll
  for (int f = 0; f < 10; ++f) tr[f] = (to < 10) ? trans[to * 10 + f] : 0.f;
  float fv = (to == 8) ? 0.f : -10000.f;   // START_TAG = 8

  float fbuf[8];
#pragma unroll
  for (int i = 0; i < 8; ++i) fbuf[i] = (to < 10) ? g_feats[i * 10 + to] : 0.f;

  for (int t = 0; t < 4096; t += 8) {
#pragma unroll
    for (int u = 0; u < 8; ++u) {
      const int tt = t + u;
      float m = -3.4e38f; int am = 0;
#pragma unroll
      for (int f = 0; f < 10; ++f) {
        float v = __shfl(fv, f) + tr[f];
        if (v > m) { m = v; am = f; }
      }
      float ft = fbuf[u];
      if (tt + 8 < 4096 && to < 10) fbuf[u] = g_feats[(tt + 8) * 10 + to];
      fv = m + ft;
      if (to < 10) bps[tt * 10 + to] = (unsigned char)am;
    }
  }
  __syncthreads();

  float term = fv + ((to < 10) ? trans[90 + to] : -3.4e38f);  // STOP_TAG row
  float best = -3.4e38f; int bl = 0;
#pragma unroll
  for (int f = 0; f < 10; ++f) {
    float v = __shfl(term, f);
    if (v > best) { best = v; bl = f; }
  }
  if (to == 0) {
    out[0] = best;
    int tag = bl;
    for (int t = 4095; t >= 0; --t) {
      out[1 + t] = (float)tag;
      tag = bps[t * 10 + tag];
    }
  }
}

// ---------------- launch ----------------
extern "C" void kernel_launch(void* const* d_in, const int* in_sizes, int n_in,
                              void* d_out, int out_size, void* d_ws, size_t ws_size,
                              hipStream_t stream)
{
  (void)in_sizes; (void)n_in; (void)out_size; (void)d_ws; (void)ws_size;
  const float* W_hh_f   = (const float*)d_in[2];
  const float* b_f      = (const float*)d_in[3];
  const float* W_hh_b   = (const float*)d_in[5];
  const float* b_b      = (const float*)d_in[6];
  const float* W_lin    = (const float*)d_in[7];
  const float* b_lin    = (const float*)d_in[8];
  const float* trans    = (const float*)d_in[9];

  cvt_split<<<1024, 256, 0, stream>>>((const float*)d_in[0], 0, 2097152);
  cvt_split<<<1024, 256, 0, stream>>>((const float*)d_in[1], 1, 2097152);
  cvt_split<<<1024, 256, 0, stream>>>((const float*)d_in[4], 2, 2097152);

  gemm_xp<<<dim3(32, 32, 2), 256, 0, stream>>>(b_f, b_b);

  init_sync<<<16, 1024, 0, stream>>>();

  lstm_persistent<<<256, 1024, 0, stream>>>(W_hh_f, W_hh_b);

  feats_kernel<<<256, 256, 0, stream>>>(W_lin, b_lin);

  viterbi_kernel<<<1, 64, 0, stream>>>(trans, (float*)d_out);
}

// Round 10
// 10569.454 us; speedup vs baseline: 2.2165x; 1.1584x over previous
//
#include <hip/hip_runtime.h>

typedef _Float16 f16;
typedef _Float16 f16x2 __attribute__((ext_vector_type(2)));
typedef _Float16 f16x4 __attribute__((ext_vector_type(4)));
typedef _Float16 f16x8 __attribute__((ext_vector_type(8)));
typedef float f32x4 __attribute__((ext_vector_type(4)));
typedef unsigned u32x4 __attribute__((ext_vector_type(4)));

#define SEQ 4096
#define NF  2048
#define HID 1024
#define SENT 0x7F800001u   // sNaN bit pattern: "not ready" sentinel (h is never NaN)

#if __has_builtin(__builtin_amdgcn_fdot2)
#define FDOT2(a, b, c) __builtin_amdgcn_fdot2((a), (b), (c), false)
#else
#define FDOT2(a, b, c) ((float)(a).x * (float)(b).x + (float)(a).y * (float)(b).y + (c))
#endif

// ---------------- static device scratch ----------------
__device__ f16   g_Ahi[SEQ * NF];
__device__ f16   g_Alo[SEQ * NF];
__device__ f16   g_Whi[2 * 4096 * NF];
__device__ f16   g_Wlo[2 * 4096 * NF];
__device__ float g_xp [2u * SEQ * 4096u];          // [dir][t][4096]
__device__ float g_hist[2u * SEQ * HID];           // [dir][t][1024]
__device__ float g_ring[2][8][1024];               // [dir][slot][dim] : h bits or SENT
__device__ float g_feats[SEQ * 10];

// ---------------- fp32 -> f16 hi/lo split ----------------
__global__ void cvt_split(const float* __restrict__ src, int which, int n4) {
  int i = blockIdx.x * blockDim.x + threadIdx.x;
  int stride = gridDim.x * blockDim.x;
  f16* hi; f16* lo;
  if (which == 0)      { hi = g_Ahi; lo = g_Alo; }
  else if (which == 1) { hi = g_Whi; lo = g_Wlo; }
  else                 { hi = g_Whi + 4096 * NF; lo = g_Wlo + 4096 * NF; }
  const float4* s4 = (const float4*)src;
  f16x4* h4 = (f16x4*)hi;
  f16x4* l4 = (f16x4*)lo;
  for (int idx = i; idx < n4; idx += stride) {
    float4 v = s4[idx];
    f16x4 h, l;
    h.x = (f16)v.x; l.x = (f16)(v.x - (float)h.x);
    h.y = (f16)v.y; l.y = (f16)(v.y - (float)h.y);
    h.z = (f16)v.z; l.z = (f16)(v.z - (float)h.z);
    h.w = (f16)v.w; l.w = (f16)(v.w - (float)h.w);
    h4[idx] = h; l4[idx] = l;
  }
}

// ---------------- xp = A @ W^T + b  (split f16, 3 MFMA products) ----------------
__global__ __launch_bounds__(256, 1) void gemm_xp(
    const float* __restrict__ b_f, const float* __restrict__ b_b)
{
  const int d = blockIdx.z;
  const f16* WhiD = g_Whi + (size_t)d * (4096u * 2048u);
  const f16* WloD = g_Wlo + (size_t)d * (4096u * 2048u);
  const float* bias = d ? b_b : b_f;
  float* out = g_xp + (size_t)d * (4096u * 4096u);

  __shared__ f16 sAh[128 * 40];
  __shared__ f16 sAl[128 * 40];
  __shared__ f16 sWh[128 * 40];
  __shared__ f16 sWl[128 * 40];

  const int tid  = threadIdx.x;
  const int lane = tid & 63;
  const int wv   = tid >> 6;
  const int quad = lane >> 4;
  const int mrow = lane & 15;
  const int m0 = (wv & 1) * 64;
  const int n0 = (wv >> 1) * 64;
  const int bm = blockIdx.y, bn = blockIdx.x;

  f32x4 acc[4][4] = {};

  const int r0  = tid >> 2;
  const int seg = tid & 3;

  for (int kt = 0; kt < 2048; kt += 32) {
#pragma unroll
    for (int r = 0; r < 2; ++r) {
      int row = r * 64 + r0;
      size_t ga = (size_t)(bm * 128 + row) * 2048 + kt + seg * 8;
      size_t gw = (size_t)(bn * 128 + row) * 2048 + kt + seg * 8;
      int lidx = row * 40 + seg * 8;
      *(f16x8*)&sAh[lidx] = *(const f16x8*)&g_Ahi[ga];
      *(f16x8*)&sAl[lidx] = *(const f16x8*)&g_Alo[ga];
      *(f16x8*)&sWh[lidx] = *(const f16x8*)&WhiD[gw];
      *(f16x8*)&sWl[lidx] = *(const f16x8*)&WloD[gw];
    }
    __syncthreads();

    f16x8 ah[4], al[4], wh[4], wl[4];
#pragma unroll
    for (int mi = 0; mi < 4; ++mi) {
      int rowm = (m0 + mi * 16 + mrow) * 40 + quad * 8;
      ah[mi] = *(const f16x8*)&sAh[rowm];
      al[mi] = *(const f16x8*)&sAl[rowm];
    }
#pragma unroll
    for (int ni = 0; ni < 4; ++ni) {
      int rown = (n0 + ni * 16 + mrow) * 40 + quad * 8;
      wh[ni] = *(const f16x8*)&sWh[rown];
      wl[ni] = *(const f16x8*)&sWl[rown];
    }
#pragma unroll
    for (int mi = 0; mi < 4; ++mi)
#pragma unroll
      for (int ni = 0; ni < 4; ++ni) {
        acc[mi][ni] = __builtin_amdgcn_mfma_f32_16x16x32_f16(ah[mi], wh[ni], acc[mi][ni], 0, 0, 0);
        acc[mi][ni] = __builtin_amdgcn_mfma_f32_16x16x32_f16(ah[mi], wl[ni], acc[mi][ni], 0, 0, 0);
        acc[mi][ni] = __builtin_amdgcn_mfma_f32_16x16x32_f16(al[mi], wh[ni], acc[mi][ni], 0, 0, 0);
      }
    __syncthreads();
  }

#pragma unroll
  for (int ni = 0; ni < 4; ++ni) {
    int g = bn * 128 + n0 + ni * 16 + mrow;
    float bv = bias[g];
#pragma unroll
    for (int mi = 0; mi < 4; ++mi) {
#pragma unroll
      for (int r = 0; r < 4; ++r) {
        int t = bm * 128 + m0 + mi * 16 + quad * 4 + r;
        out[(size_t)t * 4096 + g] = acc[mi][ni][r] + bv;
      }
    }
  }
}

// ---------------- per-call ring reset (graph-replay safe) ----------------
// slot 0 = h_0 = 0.0f (real values, consumed at t=1); slots 1..7 = SENT.
__global__ void init_sync() {
  int i = blockIdx.x * blockDim.x + threadIdx.x;   // 0..16383
  int slot = (i >> 10) & 7;
  ((unsigned*)g_ring)[i] = (slot == 0) ? 0u : SENT;
}

// ---------------- persistent bidirectional LSTM ----------------
// R15 = R11 (proven 8.78 ms, absmax 0.0: 1-deep FUSED poll, coalesced
// single-wave stores, 2 barriers, grid 256x1024, dir=bid&3) with ONE
// change: the recurrent GEMV uses f16 inputs + v_dot2_f32_f16 (f32
// accumulate). Rationale: R14 showed poll oversampling backfires (slower
// AND dirty -> 2-deep poll retired); chain budget at R11 puts GEMV issue
// (~1.0us: 4 waves/SIMD x ~320 instrs x 2cy) as the largest segment.
// dot2 halves both FMA count (64->32) and LDS reads (16 b128 -> 16 b64):
// GEMV issue ~0.5us. Precision: f16 products, f32 accumulation; xp (the
// dominant gate term) remains fp32 from the split-f16 MFMA GEMM. Expected
// score drift O(1-10), threshold 142 (R14 empirically confirmed absmax 32
// passes). Sync protocol/byte layout untouched (ring stays fp32).
__global__ __launch_bounds__(1024) void lstm_persistent(
    const float* __restrict__ Whh_f, const float* __restrict__ Whh_b)
{
  const int bid = blockIdx.x;
  const int dir = bid & 3;
  if (dir >= 2) return;            // 128 of 256 WGs exit immediately
  const int wsl = bid >> 2;        // 0..63 (dims [16*wsl, 16*wsl+16))
  const int tid = threadIdx.x;
  const int r   = tid >> 4;        // local row 0..63 (gate = r>>4, jj = r&15)
  const int l16 = tid & 15;

  __shared__ f16   h16[1024];      // h_{t-1} as f16 (packed by loaders)
  __shared__ float gates_lds[64];

  const float* Wd = dir ? Whh_b : Whh_f;

  // one-time weight load: row grow, cols 4*l16 + 64*j, converted to f16x2
  const int grow = (r >> 4) * 1024 + wsl * 16 + (r & 15);
  f16x2 w2[32];
#pragma unroll
  for (int j = 0; j < 16; ++j) {
    float4 wv = *(const float4*)&Wd[(size_t)grow * 1024 + 4 * l16 + 64 * j];
    f16x2 a, b;
    a.x = (f16)wv.x; a.y = (f16)wv.y;
    b.x = (f16)wv.z; b.y = (f16)wv.w;
    w2[2 * j]     = a;
    w2[2 * j + 1] = b;
  }

  const float* xpd = g_xp + (size_t)dir * 4096u * 4096u;
  float* histd = g_hist + (size_t)dir * 4096u * 1024u;
  float* ringd = &g_ring[dir][0][0];   // [slot][1024]

  float c = 0.f;

  for (int t = 1; t <= 4096; ++t) {
    const int tau = dir ? (4096 - t) : (t - 1);

    // prefetch xp contribution (consumed in the update stage)
    float xv0 = 0.f, xv1 = 0.f, xv2 = 0.f, xv3 = 0.f;
    if (tid < 16) {
      const float* px = xpd + (size_t)tau * 4096 + wsl * 16 + tid;
      xv0 = px[0]; xv1 = px[1024]; xv2 = px[2048]; xv3 = px[3072];
    }

    // poll ring for h_{t-1}: 256 loader threads, 4 dims (16B) each, via the
    // PROVEN fused load+waitcnt pattern (R5/R7/R11: absmax 0.0). Ready <=>
    // no lane of the 16B equals SENT. Loaders convert to f16 for LDS.
    if (tid < 256) {
      const float* rs = ringd + (size_t)((t - 1) & 7) * 1024 + 4 * tid;
      u32x4 q;
      for (;;) {
        asm volatile("global_load_dwordx4 %0, %1, off sc0 sc1\n\t"
                     "s_waitcnt vmcnt(0)"
                     : "=v"(q) : "v"(rs) : "memory");
        if (q.x != SENT && q.y != SENT && q.z != SENT && q.w != SENT) break;
        __builtin_amdgcn_s_sleep(1);
      }
      f16x4 hv;
      hv.x = (f16)__uint_as_float(q.x);
      hv.y = (f16)__uint_as_float(q.y);
      hv.z = (f16)__uint_as_float(q.z);
      hv.w = (f16)__uint_as_float(q.w);
      *(f16x4*)&h16[4 * tid] = hv;   // 8B ds_write_b64
    }
    __syncthreads();

    // GEMV: 1 row x 64 k per thread via 32 x v_dot2_f32_f16 (f32 accum),
    // 16 x ds_read_b64, 4-way ILP partials
    float p0 = 0.f, p1 = 0.f, p2 = 0.f, p3 = 0.f;
#pragma unroll
    for (int j = 0; j < 16; j += 4) {
      f16x4 a0 = *(const f16x4*)&h16[4 * l16 + 64 * (j + 0)];
      f16x4 a1 = *(const f16x4*)&h16[4 * l16 + 64 * (j + 1)];
      f16x4 a2 = *(const f16x4*)&h16[4 * l16 + 64 * (j + 2)];
      f16x4 a3 = *(const f16x4*)&h16[4 * l16 + 64 * (j + 3)];
      f16x2 a0l = __builtin_shufflevector(a0, a0, 0, 1), a0h = __builtin_shufflevector(a0, a0, 2, 3);
      f16x2 a1l = __builtin_shufflevector(a1, a1, 0, 1), a1h = __builtin_shufflevector(a1, a1, 2, 3);
      f16x2 a2l = __builtin_shufflevector(a2, a2, 0, 1), a2h = __builtin_shufflevector(a2, a2, 2, 3);
      f16x2 a3l = __builtin_shufflevector(a3, a3, 0, 1), a3h = __builtin_shufflevector(a3, a3, 2, 3);
      p0 = FDOT2(a0l, w2[2*(j+0)],     p0);
      p0 = FDOT2(a0h, w2[2*(j+0) + 1], p0);
      p1 = FDOT2(a1l, w2[2*(j+1)],     p1);
      p1 = FDOT2(a1h, w2[2*(j+1) + 1], p1);
      p2 = FDOT2(a2l, w2[2*(j+2)],     p2);
      p2 = FDOT2(a2h, w2[2*(j+2) + 1], p2);
      p3 = FDOT2(a3l, w2[2*(j+3)],     p3);
      p3 = FDOT2(a3h, w2[2*(j+3) + 1], p3);
    }
    float acc = (p0 + p1) + (p2 + p3);
    acc += __shfl_xor(acc, 1);
    acc += __shfl_xor(acc, 2);
    acc += __shfl_xor(acc, 4);
    acc += __shfl_xor(acc, 8);
    if (l16 == 0) gates_lds[r] = acc;
    __syncthreads();

    // cell update: 16 h-dims, one per thread 0..15 (single-wave, so the
    // ring/hist stores below stay COALESCED 64B single transactions)
    if (tid < 16) {
      float gi = gates_lds[tid]      + xv0;
      float gf = gates_lds[16 + tid] + xv1;
      float gg = gates_lds[32 + tid] + xv2;
      float go = gates_lds[48 + tid] + xv3;
      float si = 1.f / (1.f + __expf(-gi));
      float sf = 1.f / (1.f + __expf(-gf));
      float so = 1.f / (1.f + __expf(-go));
      float tg = 1.f - 2.f / (1.f + __expf(2.f * gg));
      c = sf * c + si * tg;
      float th = 1.f - 2.f / (1.f + __expf(2.f * c));
      float h  = so * th;
      const int dim = wsl * 16 + tid;
      // ring store FIRST (the critical chain), raw 4B f32 bits
      __hip_atomic_store((unsigned*)&ringd[(size_t)(t & 7) * 1024 + dim],
                         __float_as_uint(h),
                         __ATOMIC_RELAXED, __HIP_MEMORY_SCOPE_AGENT);
      // re-arm the slot 4 steps ahead (off critical path; same-thread
      // same-address ordering + the production chain make it safe)
      if (t + 4 <= 4096)
        __hip_atomic_store((unsigned*)&ringd[(size_t)((t + 4) & 7) * 1024 + dim],
                           SENT,
                           __ATOMIC_RELAXED, __HIP_MEMORY_SCOPE_AGENT);
      histd[(size_t)tau * 1024 + dim] = h;
    }
    // no trailing barrier: h16 rewrites in t+1 are fenced by the post-GEMV
    // barrier of step t; gates_lds rewrites by the post-poll barrier of t+1.
  }
}

// ---------------- feats = concat(h_f,h_b) @ W_lin^T + b_lin ----------------
__global__ __launch_bounds__(256, 1) void feats_kernel(
    const float* __restrict__ W_lin, const float* __restrict__ b_lin)
{
  const int tid = threadIdx.x;
  const int wv = tid >> 6, l = tid & 63;
  const int t0 = blockIdx.x * 16 + wv * 4;
  for (int it = 0; it < 4; ++it) {
    const int t = t0 + it;
    float hf[16], hbv[16];
#pragma unroll
    for (int i = 0; i < 16; ++i) hf[i]  = g_hist[(size_t)t * 1024 + l + 64 * i];
#pragma unroll
    for (int i = 0; i < 16; ++i) hbv[i] = g_hist[(size_t)(4096 + t) * 1024 + l + 64 * i];
#pragma unroll
    for (int tag = 0; tag < 10; ++tag) {
      float a = 0.f;
#pragma unroll
      for (int i = 0; i < 16; ++i) {
        a += W_lin[tag * 2048 + l + 64 * i] * hf[i];
        a += W_lin[tag * 2048 + 1024 + l + 64 * i] * hbv[i];
      }
      a += __shfl_xor(a, 32); a += __shfl_xor(a, 16); a += __shfl_xor(a, 8);
      a += __shfl_xor(a, 4);  a += __shfl_xor(a, 2);  a += __shfl_xor(a, 1);
      if (l == 0) g_feats[t * 10 + tag] = a + b_lin[tag];
    }
  }
}

// ---------------- Viterbi forward + backtrack ----------------
__global__ __launch_bounds__(64, 1) void viterbi_kernel(
    const float* __restrict__ trans, float* __restrict__ out)
{
  __shared__ unsigned char bps[4096 * 10];
  const int to = threadIdx.x;
  float tr[10];
#pragma unroll
  for (int f = 0; f < 10; ++f) tr[f] = (to < 10) ? trans[to * 10 + f] : 0.f;
  float fv = (to == 8) ? 0.f : -10000.f;   // START_TAG = 8

  float fbuf[8];
#pragma unroll
  for (int i = 0; i < 8; ++i) fbuf[i] = (to < 10) ? g_feats[i * 10 + to] : 0.f;

  for (int t = 0; t < 4096; t += 8) {
#pragma unroll
    for (int u = 0; u < 8; ++u) {
      const int tt = t + u;
      float m = -3.4e38f; int am = 0;
#pragma unroll
      for (int f = 0; f < 10; ++f) {
        float v = __shfl(fv, f) + tr[f];
        if (v > m) { m = v; am = f; }
      }
      float ft = fbuf[u];
      if (tt + 8 < 4096 && to < 10) fbuf[u] = g_feats[(tt + 8) * 10 + to];
      fv = m + ft;
      if (to < 10) bps[tt * 10 + to] = (unsigned char)am;
    }
  }
  __syncthreads();

  float term = fv + ((to < 10) ? trans[90 + to] : -3.4e38f);  // STOP_TAG row
  float best = -3.4e38f; int bl = 0;
#pragma unroll
  for (int f = 0; f < 10; ++f) {
    float v = __shfl(term, f);
    if (v > best) { best = v; bl = f; }
  }
  if (to == 0) {
    out[0] = best;
    int tag = bl;
    for (int t = 4095; t >= 0; --t) {
      out[1 + t] = (float)tag;
      tag = bps[t * 10 + tag];
    }
  }
}

// ---------------- launch ----------------
extern "C" void kernel_launch(void* const* d_in, const int* in_sizes, int n_in,
                              void* d_out, int out_size, void* d_ws, size_t ws_size,
                              hipStream_t stream)
{
  (void)in_sizes; (void)n_in; (void)out_size; (void)d_ws; (void)ws_size;
  const float* W_hh_f   = (const float*)d_in[2];
  const float* b_f      = (const float*)d_in[3];
  const float* W_hh_b   = (const float*)d_in[5];
  const float* b_b      = (const float*)d_in[6];
  const float* W_lin    = (const float*)d_in[7];
  const float* b_lin    = (const float*)d_in[8];
  const float* trans    = (const float*)d_in[9];

  cvt_split<<<1024, 256, 0, stream>>>((const float*)d_in[0], 0, 2097152);
  cvt_split<<<1024, 256, 0, stream>>>((const float*)d_in[1], 1, 2097152);
  cvt_split<<<1024, 256, 0, stream>>>((const float*)d_in[4], 2, 2097152);

  gemm_xp<<<dim3(32, 32, 2), 256, 0, stream>>>(b_f, b_b);

  init_sync<<<16, 1024, 0, stream>>>();

  lstm_persistent<<<256, 1024, 0, stream>>>(W_hh_f, W_hh_b);

  feats_kernel<<<256, 256, 0, stream>>>(W_lin, b_lin);

  viterbi_kernel<<<1, 64, 0, stream>>>(trans, (float*)d_out);
}